// Round 1
// baseline (1361.971 us; speedup 1.0000x reference)
//
#include <hip/hip_runtime.h>

#define D 128
#define NLAYERS 3
#define BN_EPS 1e-5f

// ---------------- setup kernels ----------------

__global__ void k_hist_edges(const int* __restrict__ dst, int* __restrict__ cnt, int E) {
    int i = blockIdx.x * blockDim.x + threadIdx.x;
    if (i < E) atomicAdd(&cnt[dst[i]], 1);
}

__global__ void k_hist_batch(const int* __restrict__ batch, int* __restrict__ gcnt, int N) {
    int i = blockIdx.x * blockDim.x + threadIdx.x;
    if (i < N) atomicAdd(&gcnt[batch[i]], 1);
}

__global__ void k_dinv(const int* __restrict__ cnt, float* __restrict__ dinv, int N) {
    int i = blockIdx.x * blockDim.x + threadIdx.x;
    if (i < N) dinv[i] = rsqrtf((float)(cnt[i] + 1));   // +1 self loop
}

// partial sums of blocks of 1024 counts
__global__ void k_scan_partial(const int* __restrict__ cnt, int* __restrict__ bsum, int N) {
    __shared__ int sh[256];
    int b = blockIdx.x, t = threadIdx.x;
    int base = b * 1024 + t * 4;
    int s = 0;
#pragma unroll
    for (int i = 0; i < 4; ++i) { int idx = base + i; s += (idx < N) ? cnt[idx] : 0; }
    sh[t] = s;
    for (int ofs = 128; ofs > 0; ofs >>= 1) {
        __syncthreads();
        if (t < ofs) sh[t] += sh[t + ofs];
    }
    __syncthreads();
    if (t == 0) bsum[b] = sh[0];
}

// exclusive scan of up to 256 block sums (single block, 256 threads)
__global__ void k_scan_small(const int* __restrict__ bsum, int* __restrict__ bbase, int nb) {
    __shared__ int sh[256];
    int t = threadIdx.x;
    int v = (t < nb) ? bsum[t] : 0;
    sh[t] = v;
    __syncthreads();
    for (int ofs = 1; ofs < 256; ofs <<= 1) {
        int vv = (t >= ofs) ? sh[t - ofs] : 0;
        __syncthreads();
        sh[t] += vv;
        __syncthreads();
    }
    bbase[t] = sh[t] - v;   // exclusive
}

__global__ void k_scan_apply(const int* __restrict__ cnt, const int* __restrict__ bbase,
                             int* __restrict__ roff, int* __restrict__ cur, int N) {
    __shared__ int sh[256];
    int b = blockIdx.x, t = threadIdx.x;
    int base = b * 1024 + t * 4;
    int v[4]; int s = 0;
#pragma unroll
    for (int i = 0; i < 4; ++i) { v[i] = (base + i < N) ? cnt[base + i] : 0; s += v[i]; }
    sh[t] = s;
    __syncthreads();
    for (int ofs = 1; ofs < 256; ofs <<= 1) {
        int vv = (t >= ofs) ? sh[t - ofs] : 0;
        __syncthreads();
        sh[t] += vv;
        __syncthreads();
    }
    int o = bbase[b] + sh[t] - s;
#pragma unroll
    for (int i = 0; i < 4; ++i) {
        int idx = base + i;
        if (idx < N) {
            roff[idx] = o; cur[idx] = o;
            o += v[i];
            if (idx == N - 1) roff[N] = o;
        }
    }
}

// scan of graph counts (G <= 1024), single block of 256 threads
__global__ void k_gscan(const int* __restrict__ gcnt, int* __restrict__ goff, int G, int N) {
    __shared__ int sh[256];
    int t = threadIdx.x;
    int base = t * 4;
    int v[4]; int s = 0;
#pragma unroll
    for (int i = 0; i < 4; ++i) { v[i] = (base + i < G) ? gcnt[base + i] : 0; s += v[i]; }
    sh[t] = s;
    __syncthreads();
    for (int ofs = 1; ofs < 256; ofs <<= 1) {
        int vv = (t >= ofs) ? sh[t - ofs] : 0;
        __syncthreads();
        sh[t] += vv;
        __syncthreads();
    }
    int o = sh[t] - s;
#pragma unroll
    for (int i = 0; i < 4; ++i) {
        int idx = base + i;
        if (idx < G) { goff[idx] = o; o += v[i]; }
    }
    if (t == 255) goff[G] = N;
}

__global__ void k_fill(const int* __restrict__ src, const int* __restrict__ dst,
                       int* __restrict__ cur, int* __restrict__ csr, int E) {
    int i = blockIdx.x * blockDim.x + threadIdx.x;
    if (i < E) {
        int p = atomicAdd(&cur[dst[i]], 1);
        csr[p] = src[i];
    }
}

__global__ void k_init_ac(float* __restrict__ a, float* __restrict__ c) {
    int t = threadIdx.x;
    a[t] = 1.0f; c[t] = 0.0f;
}

// Wf[k][j] = a[k]*W[k][j], same for rW
__global__ void k_fold_scale(const float* __restrict__ W, const float* __restrict__ rW,
                             const float* __restrict__ a,
                             float* __restrict__ Wf, float* __restrict__ rWf) {
    int idx = blockIdx.x * 256 + threadIdx.x;  // grid 128 -> 32768 threads
    if (idx < D * D) {
        int k = idx >> 7;
        Wf[idx] = a[k] * W[idx];
    } else {
        int li = idx - D * D;
        int k = li >> 7;
        rWf[li] = a[k] * rW[li];
    }
}

// cwA[j] = sum_k c[k]*W[k][j];  crb[j] = rb[j] + sum_k c[k]*rW[k][j]
__global__ void k_fold_vec(const float* __restrict__ W, const float* __restrict__ rW,
                           const float* __restrict__ c, const float* __restrict__ rb,
                           float* __restrict__ cwA, float* __restrict__ crb) {
    int t = threadIdx.x;  // 256
    if (t < D) {
        float s = 0.f;
        for (int k = 0; k < D; ++k) s += c[k] * W[k * D + t];
        cwA[t] = s;
    } else {
        int j = t - D;
        float s = rb[j];
        for (int k = 0; k < D; ++k) s += c[k] * rW[k * D + j];
        crb[j] = s;
    }
}

// ---------------- fused dual GEMM ----------------
// O0 = F @ W0 + add0 ;  O1 = relu(F @ W1 + add1)
// block: 256 threads, 128-row tile, full 128 cols, 8x8 per-thread micro-tile.
__global__ __launch_bounds__(256) void k_gemm_dual(
    const float* __restrict__ F,
    const float* __restrict__ W0, const float* __restrict__ W1,
    const float* __restrict__ add0, const float* __restrict__ add1,
    float* __restrict__ O0, float* __restrict__ O1, int N) {
    __shared__ float fs[128 * 128];
    const int t = threadIdx.x;
    const int rowbase = blockIdx.x * 128;

    // stage 128x128 f tile, XOR-swizzled on 16B units: su = unit ^ ((row>>3)&7)
#pragma unroll
    for (int i = 0; i < 16; ++i) {
        int l = t + i * 256;          // float4 index 0..4095
        int row = l >> 5;
        int unit = l & 31;
        float4 v = make_float4(0.f, 0.f, 0.f, 0.f);
        int gr = rowbase + row;
        if (gr < N) v = *(const float4*)(F + (size_t)gr * D + unit * 4);
        int su = unit ^ ((row >> 3) & 7);
        *(float4*)&fs[row * 128 + su * 4] = v;
    }
    __syncthreads();

    const int tx = t & 15, ty = t >> 4;
    const int c0 = tx * 8;
    const int r0 = ty * 8;

#pragma unroll 1
    for (int m = 0; m < 2; ++m) {
        const float* __restrict__ W = m ? W1 : W0;
        const float* __restrict__ addv = m ? add1 : add0;
        float* __restrict__ O = m ? O1 : O0;

        float acc[8][8];
#pragma unroll
        for (int i = 0; i < 8; ++i)
#pragma unroll
            for (int j = 0; j < 8; ++j) acc[i][j] = 0.f;

        for (int kc = 0; kc < 128; kc += 4) {
            float fr[8][4];
#pragma unroll
            for (int i = 0; i < 8; ++i) {
                int rr = r0 + i;
                int su = (kc >> 2) ^ ((rr >> 3) & 7);
                float4 t4 = *(const float4*)&fs[rr * 128 + su * 4];
                fr[i][0] = t4.x; fr[i][1] = t4.y; fr[i][2] = t4.z; fr[i][3] = t4.w;
            }
#pragma unroll
            for (int kk = 0; kk < 4; ++kk) {
                float4 wa = *(const float4*)(W + (size_t)(kc + kk) * D + c0);
                float4 wb = *(const float4*)(W + (size_t)(kc + kk) * D + c0 + 4);
                float wv[8] = {wa.x, wa.y, wa.z, wa.w, wb.x, wb.y, wb.z, wb.w};
#pragma unroll
                for (int i = 0; i < 8; ++i) {
                    float fv = fr[i][kk];
#pragma unroll
                    for (int j = 0; j < 8; ++j) acc[i][j] += fv * wv[j];
                }
            }
        }

        float va[8];
#pragma unroll
        for (int j = 0; j < 8; ++j) va[j] = addv[c0 + j];

#pragma unroll
        for (int i = 0; i < 8; ++i) {
            int gr = rowbase + r0 + i;
            if (gr < N) {
                float o0 = acc[i][0] + va[0], o1 = acc[i][1] + va[1];
                float o2 = acc[i][2] + va[2], o3 = acc[i][3] + va[3];
                float o4 = acc[i][4] + va[4], o5 = acc[i][5] + va[5];
                float o6 = acc[i][6] + va[6], o7 = acc[i][7] + va[7];
                if (m == 1) {
                    o0 = fmaxf(o0, 0.f); o1 = fmaxf(o1, 0.f); o2 = fmaxf(o2, 0.f); o3 = fmaxf(o3, 0.f);
                    o4 = fmaxf(o4, 0.f); o5 = fmaxf(o5, 0.f); o6 = fmaxf(o6, 0.f); o7 = fmaxf(o7, 0.f);
                }
                float4 lo = make_float4(o0, o1, o2, o3);
                float4 hi = make_float4(o4, o5, o6, o7);
                *(float4*)(O + (size_t)gr * D + c0) = lo;
                *(float4*)(O + (size_t)gr * D + c0 + 4) = hi;
            }
        }
    }
}

// ---------------- aggregation + residual + BN stats ----------------
// resf is read for own row then overwritten with the layer output (in-place).
__global__ __launch_bounds__(256) void k_agg(
    const float* __restrict__ h, float* __restrict__ resf,
    const int* __restrict__ roff, const int* __restrict__ csr,
    const float* __restrict__ dinv, const float* __restrict__ bias,
    float* __restrict__ stats, int N) {
    const int lane = threadIdx.x & 63;
    const int wid = (blockIdx.x * blockDim.x + threadIdx.x) >> 6;
    const int nw = (gridDim.x * blockDim.x) >> 6;
    const int c = lane * 2;
    const float b0 = bias[c], b1 = bias[c + 1];
    float sx = 0.f, sy = 0.f, qx = 0.f, qy = 0.f;

    for (int v = wid; v < N; v += nw) {
        int e = roff[v], end = roff[v + 1];
        float ax = 0.f, ay = 0.f;
        for (; e < end; ++e) {
            int u = csr[e];
            float w = dinv[u];
            const float2 hv = *(const float2*)(h + (size_t)u * D + c);
            ax += w * hv.x;
            ay += w * hv.y;
        }
        float dv = dinv[v];
        const float2 hs = *(const float2*)(h + (size_t)v * D + c);
        ax = (ax + hs.x * dv) * dv + b0;
        ay = (ay + hs.y * dv) * dv + b1;
        const float2 r = *(const float2*)(resf + (size_t)v * D + c);
        float ox = ax + r.x, oy = ay + r.y;
        *(float2*)(resf + (size_t)v * D + c) = make_float2(ox, oy);
        sx += ox; sy += oy; qx += ox * ox; qy += oy * oy;
    }

    __shared__ float4 red[256];
    red[threadIdx.x] = make_float4(sx, sy, qx, qy);
    __syncthreads();
    if (threadIdx.x < 64) {
        float4 a = red[threadIdx.x];
        float4 b = red[threadIdx.x + 64];
        float4 cc = red[threadIdx.x + 128];
        float4 d = red[threadIdx.x + 192];
        float tsx = a.x + b.x + cc.x + d.x;
        float tsy = a.y + b.y + cc.y + d.y;
        float tqx = a.z + b.z + cc.z + d.z;
        float tqy = a.w + b.w + cc.w + d.w;
        atomicAdd(&stats[c], tsx);
        atomicAdd(&stats[c + 1], tsy);
        atomicAdd(&stats[D + c], tqx);
        atomicAdd(&stats[D + c + 1], tqy);
    }
}

__global__ void k_bnfin(const float* __restrict__ stats, const float* __restrict__ gamma,
                        const float* __restrict__ beta,
                        float* __restrict__ a_next, float* __restrict__ c_next, float invN) {
    int t = threadIdx.x;  // 128
    float mean = stats[t] * invN;
    float var = stats[D + t] * invN - mean * mean;
    float rs = rsqrtf(var + BN_EPS);
    float a = gamma[t] * rs;
    a_next[t] = a;
    c_next[t] = beta[t] - mean * a;
}

// out[g] = (sum_{v in g} f[v]) * a + cnt_g * c
__global__ void k_pool(const float* __restrict__ f, const int* __restrict__ goff,
                       const float* __restrict__ a, const float* __restrict__ c,
                       float* __restrict__ out) {
    int g = blockIdx.x, t = threadIdx.x;  // 128 threads
    int beg = goff[g], end = goff[g + 1];
    float acc = 0.f;
    for (int v = beg; v < end; ++v) acc += f[(size_t)v * D + t];
    out[(size_t)g * D + t] = acc * a[t] + (float)(end - beg) * c[t];
}

// ---------------- launcher ----------------

extern "C" void kernel_launch(void* const* d_in, const int* in_sizes, int n_in,
                              void* d_out, int out_size, void* d_ws, size_t ws_size,
                              hipStream_t stream) {
    const float* x      = (const float*)d_in[0];
    const int*   ei     = (const int*)d_in[1];
    const int*   batch  = (const int*)d_in[2];
    const float* Ws     = (const float*)d_in[3];
    const float* bs     = (const float*)d_in[4];
    const float* rWs    = (const float*)d_in[5];
    const float* rbs    = (const float*)d_in[6];
    const float* gammas = (const float*)d_in[7];
    const float* betas  = (const float*)d_in[8];
    float* out = (float*)d_out;

    const int N = in_sizes[2];
    const int E = in_sizes[1] / 2;
    const int G = out_size / D;
    const int* src = ei;
    const int* dst = ei + E;

    char* ws = (char*)d_ws;
    size_t off = 0;
    auto alloc = [&](size_t bytes) -> char* {
        char* p = ws + off;
        off += (bytes + 255) & ~(size_t)255;
        return p;
    };
    float* h    = (float*)alloc((size_t)N * D * 4);
    float* R0   = (float*)alloc((size_t)N * D * 4);
    float* R1   = (float*)alloc((size_t)N * D * 4);
    int*   csr  = (int*)alloc((size_t)E * 4);
    int*   roff = (int*)alloc((size_t)(N + 1) * 4);
    int*   cur  = (int*)alloc((size_t)N * 4);
    int*   cnt  = (int*)alloc((size_t)N * 4);
    float* dinv = (float*)alloc((size_t)N * 4);
    int*   gcnt = (int*)alloc((size_t)G * 4);
    int*   goff = (int*)alloc((size_t)(G + 1) * 4);
    int*   bsum = (int*)alloc(256 * 4);
    int*   bbase= (int*)alloc(256 * 4);
    float* stats= (float*)alloc((size_t)NLAYERS * 2 * D * 4);
    float* aarr = (float*)alloc((size_t)(NLAYERS + 1) * D * 4);
    float* carr = (float*)alloc((size_t)(NLAYERS + 1) * D * 4);
    float* Wf   = (float*)alloc((size_t)D * D * 4);
    float* rWf  = (float*)alloc((size_t)D * D * 4);
    float* cwA  = (float*)alloc(D * 4);
    float* crb  = (float*)alloc(D * 4);
    (void)ws_size;

    hipMemsetAsync(cnt, 0, (size_t)N * 4, stream);
    hipMemsetAsync(gcnt, 0, (size_t)G * 4, stream);
    hipMemsetAsync(stats, 0, (size_t)NLAYERS * 2 * D * 4, stream);

    k_hist_edges<<<(E + 255) / 256, 256, 0, stream>>>(dst, cnt, E);
    k_hist_batch<<<(N + 255) / 256, 256, 0, stream>>>(batch, gcnt, N);
    k_dinv<<<(N + 255) / 256, 256, 0, stream>>>(cnt, dinv, N);

    int nb = (N + 1023) / 1024;
    k_scan_partial<<<nb, 256, 0, stream>>>(cnt, bsum, N);
    k_scan_small<<<1, 256, 0, stream>>>(bsum, bbase, nb);
    k_scan_apply<<<nb, 256, 0, stream>>>(cnt, bbase, roff, cur, N);
    k_gscan<<<1, 256, 0, stream>>>(gcnt, goff, G, N);
    k_fill<<<(E + 255) / 256, 256, 0, stream>>>(src, dst, cur, csr, E);
    k_init_ac<<<1, D, 0, stream>>>(aarr, carr);

    const float* fin = x;
    float* fouts[NLAYERS] = {R0, R1, R0};
    for (int l = 0; l < NLAYERS; ++l) {
        const float* W  = Ws + (size_t)l * D * D;
        const float* rW = rWs + (size_t)l * D * D;
        const float* aP = aarr + (size_t)l * D;
        const float* cP = carr + (size_t)l * D;

        k_fold_scale<<<128, 256, 0, stream>>>(W, rW, aP, Wf, rWf);
        k_fold_vec<<<1, 256, 0, stream>>>(W, rW, cP, rbs + (size_t)l * D, cwA, crb);

        float* fo = fouts[l];
        k_gemm_dual<<<(N + 127) / 128, 256, 0, stream>>>(fin, Wf, rWf, cwA, crb, h, fo, N);
        k_agg<<<2048, 256, 0, stream>>>(h, fo, roff, csr, dinv, bs + (size_t)l * D,
                                        stats + (size_t)l * 2 * D, N);
        k_bnfin<<<1, D, 0, stream>>>(stats + (size_t)l * 2 * D, gammas + (size_t)l * D,
                                     betas + (size_t)l * D,
                                     aarr + (size_t)(l + 1) * D, carr + (size_t)(l + 1) * D,
                                     1.0f / (float)N);
        fin = fo;
    }

    k_pool<<<G, D, 0, stream>>>(fin, goff, aarr + (size_t)NLAYERS * D,
                                carr + (size_t)NLAYERS * D, out);
}